// Round 2
// baseline (346.491 us; speedup 1.0000x reference)
//
#include <hip/hip_runtime.h>
#include <hip/hip_bf16.h>

// SJLT projection: out[b, idx[d,c]] += x[b,d] * (2*sign[d,c]-1)
// B=64, D=262144, C=4, P=4096
//
// Strategy: per-block LDS histogram (P=4096 floats = 16 KB), grid = (D-chunks, B).
// Each block handles one 8192-wide chunk of d for one batch row.
//   - x read as float4 (coalesced, 16 B/lane)
//   - indices/signs read as int4 (contiguous; shared across batches -> L2/L3 hit)
//   - LDS atomicAdd into histogram (random slots -> minimal bank collisions)
//   - epilogue: one global atomicAdd per slot into out[b,:]
// d_out is zeroed each call via hipMemsetAsync (graph-capture safe).

constexpr int B_DIM = 64;
constexpr int D_DIM = 262144;
constexpr int C_DIM = 4;
constexpr int P_DIM = 4096;

constexpr int BLOCK = 256;
constexpr int CHUNK_D = 8192;                 // d's per block
constexpr int NCHUNK = D_DIM / CHUNK_D;       // 32
constexpr int ITERS = CHUNK_D / (BLOCK * 4);  // 8 float4-iterations per thread

__global__ __launch_bounds__(BLOCK) void sjlt_kernel(
    const float* __restrict__ x,
    const int* __restrict__ idx,
    const int* __restrict__ sgn,
    float* __restrict__ out) {
    __shared__ float hist[P_DIM];

    #pragma unroll
    for (int i = threadIdx.x; i < P_DIM; i += BLOCK) hist[i] = 0.0f;
    __syncthreads();

    const int b = blockIdx.y;
    const int chunk = blockIdx.x;
    const int d0 = chunk * CHUNK_D;

    const float* xrow = x + (size_t)b * D_DIM + d0;
    const int*   idxc = idx + (size_t)d0 * C_DIM;
    const int*   sgnc = sgn + (size_t)d0 * C_DIM;

    #pragma unroll
    for (int it = 0; it < ITERS; ++it) {
        const int base = it * (BLOCK * 4) + threadIdx.x * 4;  // d offset in chunk
        const float4 xv = *reinterpret_cast<const float4*>(xrow + base);

        #pragma unroll
        for (int k = 0; k < 4; ++k) {
            const int d = base + k;
            const int4 iv = *reinterpret_cast<const int4*>(idxc + d * C_DIM);
            const int4 sv = *reinterpret_cast<const int4*>(sgnc + d * C_DIM);
            const float xs = (k == 0) ? xv.x : (k == 1) ? xv.y : (k == 2) ? xv.z : xv.w;
            atomicAdd(&hist[iv.x], sv.x ? xs : -xs);
            atomicAdd(&hist[iv.y], sv.y ? xs : -xs);
            atomicAdd(&hist[iv.z], sv.z ? xs : -xs);
            atomicAdd(&hist[iv.w], sv.w ? xs : -xs);
        }
    }
    __syncthreads();

    float* orow = out + (size_t)b * P_DIM;
    #pragma unroll
    for (int p = threadIdx.x; p < P_DIM; p += BLOCK) {
        atomicAdd(&orow[p], hist[p]);
    }
}

extern "C" void kernel_launch(void* const* d_in, const int* in_sizes, int n_in,
                              void* d_out, int out_size, void* d_ws, size_t ws_size,
                              hipStream_t stream) {
    const float* x   = (const float*)d_in[0];
    const int*   idx = (const int*)d_in[1];
    const int*   sgn = (const int*)d_in[2];
    float* out = (float*)d_out;

    hipMemsetAsync(d_out, 0, (size_t)out_size * sizeof(float), stream);

    dim3 grid(NCHUNK, B_DIM);
    sjlt_kernel<<<grid, BLOCK, 0, stream>>>(x, idx, sgn, out);
}

// Round 3
// 344.121 us; speedup vs baseline: 1.0069x; 1.0069x over previous
//
#include <hip/hip_runtime.h>
#include <hip/hip_bf16.h>

// SJLT projection: out[b, idx[d,c]] += x[b,d] * (2*sign[d,c]-1)
// B=64, D=262144, C=4, P=4096
//
// R3 redesign after R2 post-mortem (339us, all pipes idle):
//  - fp32 atomicAdd compiles to a CAS loop (safe-fp-atomics default) -> use
//    unsafeAtomicAdd => native ds_add_f32 (no return, no retry loop).
//  - one d per LANE (not 4 per thread) => idx/sgn int4 loads are perfectly
//    coalesced (16 B/lane contiguous), x loads coalesced scalar.
//  - zero global atomics: blocks store per-(chunk,b) partial histograms to
//    d_ws, a second kernel reduces 16 partials -> out. (R2 showed every
//    global fp32 atomic caused an HBM write: WRITE_SIZE was 33 MB for a
//    1 MB output.) Fallback to unsafeAtomicAdd accumulation if ws is small.
//  - MULTI_B=2 rows per block: idx/sgn request traffic halved.

constexpr int B_DIM = 64;
constexpr int D_DIM = 262144;
constexpr int C_DIM = 4;
constexpr int P_DIM = 4096;

constexpr int BLOCK   = 1024;
constexpr int NCHUNK  = 16;
constexpr int CHUNK_D = D_DIM / NCHUNK;   // 16384
constexpr int MULTI_B = 2;
constexpr int NBGRP   = B_DIM / MULTI_B;  // 32
constexpr size_t WS_NEED = (size_t)NCHUNK * B_DIM * P_DIM * sizeof(float);  // 16.8 MB

__device__ __forceinline__ float signed_val(float x, int s) {
    // s in {0,1}; s=1 -> +x, s=0 -> -x  (2s-1)
    return __uint_as_float(__float_as_uint(x) ^ (((unsigned)(s ^ 1)) << 31));
}

template <bool USE_WS>
__global__ __launch_bounds__(BLOCK) void sjlt_hist(
    const float* __restrict__ x,
    const int* __restrict__ idx,
    const int* __restrict__ sgn,
    float* __restrict__ dst) {  // ws if USE_WS else out
    __shared__ float hist[MULTI_B][P_DIM];  // 32 KB

    for (int i = threadIdx.x; i < MULTI_B * P_DIM; i += BLOCK)
        (&hist[0][0])[i] = 0.0f;
    __syncthreads();

    const int chunk = blockIdx.x;
    const int bg    = blockIdx.y;
    const int d0    = chunk * CHUNK_D;
    const int b0    = bg * MULTI_B;

    const float* xr0 = x + (size_t)b0 * D_DIM + d0;
    const float* xr1 = xr0 + D_DIM;
    const int4* iv4 = reinterpret_cast<const int4*>(idx) + d0;  // [d] -> 4 ints
    const int4* sv4 = reinterpret_cast<const int4*>(sgn) + d0;

    for (int t = threadIdx.x; t < CHUNK_D; t += BLOCK) {
        const int4 iv = iv4[t];
        const int4 sv = sv4[t];
        const float x0 = xr0[t];
        const float x1 = xr1[t];

        unsafeAtomicAdd(&hist[0][iv.x], signed_val(x0, sv.x));
        unsafeAtomicAdd(&hist[0][iv.y], signed_val(x0, sv.y));
        unsafeAtomicAdd(&hist[0][iv.z], signed_val(x0, sv.z));
        unsafeAtomicAdd(&hist[0][iv.w], signed_val(x0, sv.w));
        unsafeAtomicAdd(&hist[1][iv.x], signed_val(x1, sv.x));
        unsafeAtomicAdd(&hist[1][iv.y], signed_val(x1, sv.y));
        unsafeAtomicAdd(&hist[1][iv.z], signed_val(x1, sv.z));
        unsafeAtomicAdd(&hist[1][iv.w], signed_val(x1, sv.w));
    }
    __syncthreads();

    if (USE_WS) {
        // ws[chunk][b][p]
        float* w = dst + ((size_t)chunk * B_DIM + b0) * P_DIM;
        for (int p = threadIdx.x; p < P_DIM; p += BLOCK) {
            w[p]         = hist[0][p];
            w[P_DIM + p] = hist[1][p];
        }
    } else {
        float* o = dst + (size_t)b0 * P_DIM;
        for (int p = threadIdx.x; p < P_DIM; p += BLOCK) {
            unsafeAtomicAdd(&o[p],         hist[0][p]);
            unsafeAtomicAdd(&o[P_DIM + p], hist[1][p]);
        }
    }
}

__global__ __launch_bounds__(256) void sjlt_reduce(
    const float* __restrict__ ws, float* __restrict__ out) {
    const int id = blockIdx.x * 256 + threadIdx.x;  // [0, B*P)
    float s = 0.0f;
    #pragma unroll
    for (int c = 0; c < NCHUNK; ++c)
        s += ws[(size_t)c * B_DIM * P_DIM + id];
    out[id] = s;
}

extern "C" void kernel_launch(void* const* d_in, const int* in_sizes, int n_in,
                              void* d_out, int out_size, void* d_ws, size_t ws_size,
                              hipStream_t stream) {
    const float* x   = (const float*)d_in[0];
    const int*   idx = (const int*)d_in[1];
    const int*   sgn = (const int*)d_in[2];
    float* out = (float*)d_out;
    float* ws  = (float*)d_ws;

    dim3 grid(NCHUNK, NBGRP);
    if (ws_size >= WS_NEED) {
        sjlt_hist<true><<<grid, BLOCK, 0, stream>>>(x, idx, sgn, ws);
        sjlt_reduce<<<(B_DIM * P_DIM) / 256, 256, 0, stream>>>(ws, out);
    } else {
        hipMemsetAsync(d_out, 0, (size_t)out_size * sizeof(float), stream);
        sjlt_hist<false><<<grid, BLOCK, 0, stream>>>(x, idx, sgn, out);
    }
}

// Round 4
// 218.222 us; speedup vs baseline: 1.5878x; 1.5769x over previous
//
#include <hip/hip_runtime.h>
#include <hip/hip_bf16.h>

// SJLT projection: out[b, idx[d,c]] += x[b,d] * (2*sign[d,c]-1)
// B=64, D=262144, C=4, P=4096
//
// R4 redesign. R2/R3 post-mortem: both kernels took EXACTLY 339.44 us with
// all pipes idle; the invariant was 67.1M scattered LDS-atomic lane-ops
// (~3.1 cyc/lane/CU serialized). So: eliminate atomics entirely.
//
// Ownership design (zero atomics, fully deterministic):
//   K1 pack:      pk[d].c = idx[d][c] | sign<<15          (ushort4, 2 MB ws)
//   K2 transpose: xT[d][b] = x[b][d]                      (67 MB ws)
//   K3 scan:      64 p-ranges x 32 d-slices = 2048 wave-tasks.
//                 Each wave owns a 64-slot p-range and a [64p][64b] private
//                 LDS histogram. lane = d for scanning (coalesced ushort4),
//                 lane = b for accumulating: per hit, one coalesced 256 B
//                 xT row load + plain LDS read/add/write (no races by
//                 construction). Partials -> ws (33.5 MB).
//   K4 reduce:    out[b][p] = sum over 32 d-slices of partials.
// Fallback to the R3 atomic path if ws is too small.

constexpr int B_DIM = 64;
constexpr int D_DIM = 262144;
constexpr int P_DIM = 4096;

// ---- scan geometry ----
constexpr int PR_W   = 64;               // p-slots per wave
constexpr int NPR    = P_DIM / PR_W;     // 64 p-ranges
constexpr int NDS    = 32;               // d-slices
constexpr int SLICE  = D_DIM / NDS;      // 8192
constexpr int WPB    = 4;                // waves per block
constexpr int SCAN_BLOCKS = (NPR / WPB) * NDS;  // 16*32 = 512

// ---- ws layout ----
constexpr size_t PK_OFF   = 0;
constexpr size_t PK_BYTES = (size_t)D_DIM * 4 * sizeof(unsigned short);     // 2 MB
constexpr size_t XT_OFF   = PK_OFF + PK_BYTES;
constexpr size_t XT_BYTES = (size_t)D_DIM * B_DIM * sizeof(float);          // 67 MB
constexpr size_t PART_OFF = XT_OFF + XT_BYTES;
constexpr size_t PART_BYTES = (size_t)NPR * NDS * PR_W * B_DIM * sizeof(float);  // 33.5 MB
constexpr size_t WS_NEED  = PART_OFF + PART_BYTES;                          // ~98 MB

// ---------------- K1: pack idx+sign into ushort ----------------
__global__ __launch_bounds__(256) void k_pack(
    const int* __restrict__ idx, const int* __restrict__ sgn,
    unsigned short* __restrict__ pk) {
    const int d = blockIdx.x * 256 + threadIdx.x;
    const int4 iv = reinterpret_cast<const int4*>(idx)[d];
    const int4 sv = reinterpret_cast<const int4*>(sgn)[d];
    ushort4 o;
    o.x = (unsigned short)((iv.x & 4095) | (sv.x << 15));
    o.y = (unsigned short)((iv.y & 4095) | (sv.y << 15));
    o.z = (unsigned short)((iv.z & 4095) | (sv.z << 15));
    o.w = (unsigned short)((iv.w & 4095) | (sv.w << 15));
    reinterpret_cast<ushort4*>(pk)[d] = o;
}

// ---------------- K2: transpose x[64][D] -> xT[D][64] ----------------
__global__ __launch_bounds__(256) void k_transpose(
    const float* __restrict__ x, float* __restrict__ xT) {
    __shared__ float tile[64 * 65];
    const int d0 = blockIdx.x * 64;
    const int t = threadIdx.x;
    const int lane = t & 63;
    #pragma unroll
    for (int k = 0; k < 16; ++k) {
        const int b = k * 4 + (t >> 6);
        tile[lane * 65 + b] = x[(size_t)b * D_DIM + d0 + lane];
    }
    __syncthreads();
    #pragma unroll
    for (int k = 0; k < 16; ++k) {
        const int dr = k * 4 + (t >> 6);
        xT[(size_t)(d0 + dr) * B_DIM + lane] = tile[dr * 65 + lane];
    }
}

// ---------------- K3: scan + ownership histogram ----------------
__global__ __launch_bounds__(WPB * 64) void k_scan(
    const unsigned short* __restrict__ pk,
    const float* __restrict__ xT,
    float* __restrict__ part) {
    __shared__ float hist[WPB][PR_W * B_DIM];   // 4 x 16 KB = 64 KB

    const int w    = threadIdx.x >> 6;
    const int lane = threadIdx.x & 63;          // = batch b in accumulate phase
    const int dslice  = blockIdx.x & (NDS - 1);
    const int prgroup = blockIdx.x >> 5;        // / NDS
    const int prange  = prgroup * WPB + w;
    const int p0      = prange * PR_W;
    const int dbase   = dslice * SLICE;

    float* h = hist[w];
    #pragma unroll
    for (int k = 0; k < PR_W; ++k) h[k * 64 + lane] = 0.0f;
    // no barrier needed: each wave touches only its own region

    const ushort4* pk4 = reinterpret_cast<const ushort4*>(pk);

    for (int step = 0; step < SLICE / 64; ++step) {
        const int dvec = dbase + step * 64 + lane;   // lane = d here
        const ushort4 v = pk4[dvec];

        #pragma unroll
        for (int c = 0; c < 4; ++c) {
            const unsigned u = (c == 0) ? v.x : (c == 1) ? v.y : (c == 2) ? v.z : v.w;
            const unsigned p = u & 4095u;
            const unsigned s = u >> 15;
            const unsigned off = p - (unsigned)p0;   // wraps if p < p0
            unsigned long long m = __ballot(off < (unsigned)PR_W);
            while (m) {
                const int l = __ffsll((long long)m) - 1;
                m &= m - 1;
                const int ps = __shfl((int)((off << 1) | s), l);
                const int dd = dbase + step * 64 + l;
                const float xv = xT[(size_t)dd * B_DIM + lane];  // lane = b
                const float val = (ps & 1) ? xv : -xv;
                const int a = (ps >> 1) * 64 + lane;
                h[a] += val;                                      // plain LDS RMW
            }
        }
    }

    // write partials: part[(prange*NDS + dslice)*PR_W*B + poff*B + b]
    float* wp = part + ((size_t)(prange * NDS + dslice)) * (PR_W * B_DIM);
    #pragma unroll
    for (int poff = 0; poff < PR_W; ++poff)
        wp[poff * 64 + lane] = h[poff * 64 + lane];
}

// ---------------- K4: reduce partials -> out ----------------
__global__ __launch_bounds__(256) void k_reduce(
    const float* __restrict__ part, float* __restrict__ out) {
    __shared__ float acc[PR_W * 65];
    const int pr = blockIdx.x;       // p-range
    const int t  = threadIdx.x;

    for (int i = t; i < PR_W * 65; i += 256) acc[i] = 0.0f;
    __syncthreads();

    for (int ds = 0; ds < NDS; ++ds) {
        const float* src = part + ((size_t)(pr * NDS + ds)) * (PR_W * B_DIM);
        #pragma unroll
        for (int k = 0; k < 16; ++k) {
            const int idx = k * 256 + t;           // poff*64 + b
            acc[(idx >> 6) * 65 + (idx & 63)] += src[idx];
        }
    }
    __syncthreads();

    #pragma unroll
    for (int k = 0; k < 16; ++k) {
        const int idx = k * 256 + t;
        const int b = idx >> 6, poff = idx & 63;
        out[(size_t)b * P_DIM + pr * PR_W + poff] = acc[poff * 65 + b];
    }
}

// ---------------- fallback (R3): LDS-atomic histogram ----------------
__device__ __forceinline__ float signed_val(float x, int s) {
    return __uint_as_float(__float_as_uint(x) ^ (((unsigned)(s ^ 1)) << 31));
}

__global__ __launch_bounds__(1024) void sjlt_hist_fb(
    const float* __restrict__ x, const int* __restrict__ idx,
    const int* __restrict__ sgn, float* __restrict__ out) {
    __shared__ float hist[2][P_DIM];
    for (int i = threadIdx.x; i < 2 * P_DIM; i += 1024) (&hist[0][0])[i] = 0.0f;
    __syncthreads();
    const int chunk = blockIdx.x, bg = blockIdx.y;
    const int d0 = chunk * (D_DIM / 16), b0 = bg * 2;
    const float* xr0 = x + (size_t)b0 * D_DIM + d0;
    const float* xr1 = xr0 + D_DIM;
    const int4* iv4 = reinterpret_cast<const int4*>(idx) + d0;
    const int4* sv4 = reinterpret_cast<const int4*>(sgn) + d0;
    for (int t = threadIdx.x; t < D_DIM / 16; t += 1024) {
        const int4 iv = iv4[t]; const int4 sv = sv4[t];
        const float x0 = xr0[t], x1 = xr1[t];
        unsafeAtomicAdd(&hist[0][iv.x], signed_val(x0, sv.x));
        unsafeAtomicAdd(&hist[0][iv.y], signed_val(x0, sv.y));
        unsafeAtomicAdd(&hist[0][iv.z], signed_val(x0, sv.z));
        unsafeAtomicAdd(&hist[0][iv.w], signed_val(x0, sv.w));
        unsafeAtomicAdd(&hist[1][iv.x], signed_val(x1, sv.x));
        unsafeAtomicAdd(&hist[1][iv.y], signed_val(x1, sv.y));
        unsafeAtomicAdd(&hist[1][iv.z], signed_val(x1, sv.z));
        unsafeAtomicAdd(&hist[1][iv.w], signed_val(x1, sv.w));
    }
    __syncthreads();
    float* o = out + (size_t)b0 * P_DIM;
    for (int p = threadIdx.x; p < P_DIM; p += 1024) {
        unsafeAtomicAdd(&o[p],         hist[0][p]);
        unsafeAtomicAdd(&o[P_DIM + p], hist[1][p]);
    }
}

extern "C" void kernel_launch(void* const* d_in, const int* in_sizes, int n_in,
                              void* d_out, int out_size, void* d_ws, size_t ws_size,
                              hipStream_t stream) {
    const float* x   = (const float*)d_in[0];
    const int*   idx = (const int*)d_in[1];
    const int*   sgn = (const int*)d_in[2];
    float* out = (float*)d_out;

    if (ws_size >= WS_NEED) {
        char* ws = (char*)d_ws;
        unsigned short* pk = (unsigned short*)(ws + PK_OFF);
        float* xT   = (float*)(ws + XT_OFF);
        float* part = (float*)(ws + PART_OFF);

        k_pack<<<D_DIM / 256, 256, 0, stream>>>(idx, sgn, pk);
        k_transpose<<<D_DIM / 64, 256, 0, stream>>>(x, xT);
        k_scan<<<SCAN_BLOCKS, WPB * 64, 0, stream>>>(pk, xT, part);
        k_reduce<<<NPR, 256, 0, stream>>>(part, out);
    } else {
        hipMemsetAsync(d_out, 0, (size_t)out_size * sizeof(float), stream);
        dim3 grid(16, 32);
        sjlt_hist_fb<<<grid, 1024, 0, stream>>>(x, idx, sgn, out);
    }
}

// Round 5
// 160.680 us; speedup vs baseline: 2.1564x; 1.3581x over previous
//
#include <hip/hip_runtime.h>
#include <hip/hip_bf16.h>

// SJLT projection: out[b, idx[d,c]] += x[b,d] * (2*sign[d,c]-1)
// B=64, D=262144, C=4, P=4096
//
// R5. R4 post-mortem: k_scan 168us, latency-bound (VALU 15%, HBM 5%,
// occ 21%) on a serial per-hit chain (ballot -> shfl -> global xT load
// ~600cy -> LDS RMW ~130cy). Changes:
//   1. compact hits into a per-wave LDS queue per 2048-d tile, then
//      process groups of 8 with 8 INDEPENDENT gather loads in flight;
//      branch-free duplicate-poff merge makes parallel RMW correct.
//   2. xT stored as bf16: halves transpose+gather bytes; a d-slice is
//      1 MB so 4 slices/XCD fit L2 exactly (dslice = blockIdx%32 keeps
//      same-slice blocks on one XCD) -> ~200cy gathers.
//   3. scan/compact is cheap VALU (ballot+popc), no atomics anywhere.

constexpr int B_DIM = 64;
constexpr int D_DIM = 262144;
constexpr int P_DIM = 4096;

// ---- scan geometry ----
constexpr int PR_W   = 64;               // p-slots per wave
constexpr int NPR    = P_DIM / PR_W;     // 64 p-ranges
constexpr int NDS    = 32;               // d-slices
constexpr int SLICE  = D_DIM / NDS;      // 8192
constexpr int WPB    = 4;                // waves per block
constexpr int SCAN_BLOCKS = (NPR / WPB) * NDS;  // 512
constexpr int TILE_D = 2048;             // d's per scan tile
constexpr int NTILE  = SLICE / TILE_D;   // 4
constexpr int QCAP   = 320;              // hits/tile: mean 128, sd 11 -> 17 sigma

// ---- ws layout ----
constexpr size_t PK_OFF   = 0;
constexpr size_t PK_BYTES = (size_t)D_DIM * 4 * sizeof(unsigned short);          // 2 MB
constexpr size_t XT_OFF   = PK_OFF + PK_BYTES;
constexpr size_t XT_BYTES = (size_t)D_DIM * B_DIM * sizeof(unsigned short);      // 33.5 MB
constexpr size_t PART_OFF = XT_OFF + XT_BYTES;
constexpr size_t PART_BYTES = (size_t)NPR * NDS * PR_W * B_DIM * sizeof(float);  // 33.5 MB
constexpr size_t WS_NEED  = PART_OFF + PART_BYTES;                               // ~69 MB

// ---------------- K1: pack idx+sign into ushort ----------------
__global__ __launch_bounds__(256) void k_pack(
    const int* __restrict__ idx, const int* __restrict__ sgn,
    unsigned short* __restrict__ pk) {
    const int d = blockIdx.x * 256 + threadIdx.x;
    const int4 iv = reinterpret_cast<const int4*>(idx)[d];
    const int4 sv = reinterpret_cast<const int4*>(sgn)[d];
    ushort4 o;
    o.x = (unsigned short)((iv.x & 4095) | (sv.x << 15));
    o.y = (unsigned short)((iv.y & 4095) | (sv.y << 15));
    o.z = (unsigned short)((iv.z & 4095) | (sv.z << 15));
    o.w = (unsigned short)((iv.w & 4095) | (sv.w << 15));
    reinterpret_cast<ushort4*>(pk)[d] = o;
}

// ---------------- K2: transpose x[64][D] -> xTb[D][64] (bf16) ----------------
__device__ __forceinline__ unsigned short f32_to_bf16_rne(float f) {
    unsigned u = __float_as_uint(f);
    u += 0x7FFFu + ((u >> 16) & 1u);
    return (unsigned short)(u >> 16);
}

__global__ __launch_bounds__(256) void k_transpose(
    const float* __restrict__ x, unsigned short* __restrict__ xTb) {
    __shared__ float tile[64 * 65];
    const int d0 = blockIdx.x * 64;
    const int t = threadIdx.x;
    const int lane = t & 63;
    #pragma unroll
    for (int k = 0; k < 16; ++k) {
        const int b = k * 4 + (t >> 6);
        tile[lane * 65 + b] = x[(size_t)b * D_DIM + d0 + lane];
    }
    __syncthreads();
    #pragma unroll
    for (int k = 0; k < 16; ++k) {
        const int dr = k * 4 + (t >> 6);
        xTb[(size_t)(d0 + dr) * B_DIM + lane] = f32_to_bf16_rne(tile[dr * 65 + lane]);
    }
}

// ---------------- K3: scan + compact + pipelined accumulate ----------------
__global__ __launch_bounds__(WPB * 64) void k_scan(
    const unsigned short* __restrict__ pk,
    const unsigned short* __restrict__ xTb,
    float* __restrict__ part) {
    __shared__ float hist[WPB][PR_W * B_DIM];   // 64 KB
    __shared__ unsigned q[WPB][QCAP];           // 5 KB

    const int w    = threadIdx.x >> 6;
    const int lane = threadIdx.x & 63;          // = batch b in accumulate
    const int dslice  = blockIdx.x & (NDS - 1); // same-slice blocks -> same XCD
    const int prgroup = blockIdx.x >> 5;
    const int prange  = prgroup * WPB + w;
    const unsigned p0 = (unsigned)(prange * PR_W);
    const int dbase   = dslice * SLICE;

    float* h = hist[w];
    unsigned* qw = q[w];
    #pragma unroll
    for (int k = 0; k < PR_W; ++k) h[k * 64 + lane] = 0.0f;
    // wave-private regions: no barriers anywhere

    const ushort4* pk4 = reinterpret_cast<const ushort4*>(pk);
    const unsigned long long lmask = (1ull << lane) - 1ull;

    for (int tile = 0; tile < NTILE; ++tile) {
        const int tbase = dbase + tile * TILE_D;

        // --- scan/compact this tile into the wave's queue ---
        int qn = 0;
        for (int step = 0; step < TILE_D / 64; ++step) {   // 32 steps
            const int dloc = step * 64 + lane;
            const ushort4 v = pk4[tbase + dloc];
            #pragma unroll
            for (int c = 0; c < 4; ++c) {
                const unsigned u = (c == 0) ? v.x : (c == 1) ? v.y : (c == 2) ? v.z : v.w;
                const unsigned off = (u & 4095u) - p0;     // unsigned wrap
                const bool hit = off < (unsigned)PR_W;
                const unsigned long long m = __ballot(hit);
                if (hit) {
                    const int pos = qn + __popcll(m & lmask);
                    if (pos < QCAP)
                        qw[pos] = (unsigned)dloc | (off << 11) | ((u >> 15) << 17);
                }
                qn += __popcll(m);
            }
        }
        if (qn > QCAP) qn = QCAP;   // statistically unreachable (17 sigma)

        // --- process queue: groups of 8, loads independent ---
        int i = 0;
        for (; i + 8 <= qn; i += 8) {
            unsigned e[8];
            #pragma unroll
            for (int j = 0; j < 8; ++j) e[j] = qw[i + j];   // LDS broadcast reads

            float val[8];
            unsigned a[8];
            #pragma unroll
            for (int j = 0; j < 8; ++j) {
                const unsigned dl  = e[j] & 2047u;
                const unsigned off = (e[j] >> 11) & 63u;
                const unsigned short xv = xTb[(size_t)(tbase + (int)dl) * B_DIM + lane];
                const float f = __uint_as_float((unsigned)xv << 16);
                val[j] = (e[j] >> 17) ? f : -f;
                a[j] = off * 64 + (unsigned)lane;
            }
            // branch-free duplicate merge: after this, all but the last
            // duplicate of an address carry val==0 -> parallel RMW correct
            #pragma unroll
            for (int j = 1; j < 8; ++j) {
                #pragma unroll
                for (int i2 = 0; i2 < 8; ++i2) {
                    if (i2 < j) {
                        const bool cdup = (a[i2] == a[j]);
                        val[j] += cdup ? val[i2] : 0.0f;
                        val[i2] = cdup ? 0.0f : val[i2];
                    }
                }
            }
            float hv[8];
            #pragma unroll
            for (int j = 0; j < 8; ++j) hv[j] = h[a[j]];
            #pragma unroll
            for (int j = 0; j < 8; ++j) h[a[j]] = hv[j] + val[j];
        }
        for (; i < qn; ++i) {   // tail: serial RMW
            const unsigned e = qw[i];
            const unsigned dl  = e & 2047u;
            const unsigned off = (e >> 11) & 63u;
            const unsigned short xv = xTb[(size_t)(tbase + (int)dl) * B_DIM + lane];
            const float f = __uint_as_float((unsigned)xv << 16);
            h[off * 64 + lane] += (e >> 17) ? f : -f;
        }
    }

    // write partials: part[(prange*NDS + dslice)*PR_W*B + poff*B + b]
    float* wp = part + ((size_t)(prange * NDS + dslice)) * (PR_W * B_DIM);
    #pragma unroll
    for (int poff = 0; poff < PR_W; ++poff)
        wp[poff * 64 + lane] = h[poff * 64 + lane];
}

// ---------------- K4: reduce partials -> out ----------------
__global__ __launch_bounds__(256) void k_reduce(
    const float* __restrict__ part, float* __restrict__ out) {
    __shared__ float acc[PR_W * 65];
    const int pr = blockIdx.x;
    const int t  = threadIdx.x;

    for (int i = t; i < PR_W * 65; i += 256) acc[i] = 0.0f;
    __syncthreads();

    for (int ds = 0; ds < NDS; ++ds) {
        const float* src = part + ((size_t)(pr * NDS + ds)) * (PR_W * B_DIM);
        #pragma unroll
        for (int k = 0; k < 16; ++k) {
            const int idx = k * 256 + t;
            acc[(idx >> 6) * 65 + (idx & 63)] += src[idx];
        }
    }
    __syncthreads();

    #pragma unroll
    for (int k = 0; k < 16; ++k) {
        const int idx = k * 256 + t;
        const int b = idx >> 6, poff = idx & 63;
        out[(size_t)b * P_DIM + pr * PR_W + poff] = acc[poff * 65 + b];
    }
}

// ---------------- fallback: LDS-atomic histogram ----------------
__device__ __forceinline__ float signed_val(float x, int s) {
    return __uint_as_float(__float_as_uint(x) ^ (((unsigned)(s ^ 1)) << 31));
}

__global__ __launch_bounds__(1024) void sjlt_hist_fb(
    const float* __restrict__ x, const int* __restrict__ idx,
    const int* __restrict__ sgn, float* __restrict__ out) {
    __shared__ float hist[2][P_DIM];
    for (int i = threadIdx.x; i < 2 * P_DIM; i += 1024) (&hist[0][0])[i] = 0.0f;
    __syncthreads();
    const int chunk = blockIdx.x, bg = blockIdx.y;
    const int d0 = chunk * (D_DIM / 16), b0 = bg * 2;
    const float* xr0 = x + (size_t)b0 * D_DIM + d0;
    const float* xr1 = xr0 + D_DIM;
    const int4* iv4 = reinterpret_cast<const int4*>(idx) + d0;
    const int4* sv4 = reinterpret_cast<const int4*>(sgn) + d0;
    for (int t = threadIdx.x; t < D_DIM / 16; t += 1024) {
        const int4 iv = iv4[t]; const int4 sv = sv4[t];
        const float x0 = xr0[t], x1 = xr1[t];
        unsafeAtomicAdd(&hist[0][iv.x], signed_val(x0, sv.x));
        unsafeAtomicAdd(&hist[0][iv.y], signed_val(x0, sv.y));
        unsafeAtomicAdd(&hist[0][iv.z], signed_val(x0, sv.z));
        unsafeAtomicAdd(&hist[0][iv.w], signed_val(x0, sv.w));
        unsafeAtomicAdd(&hist[1][iv.x], signed_val(x1, sv.x));
        unsafeAtomicAdd(&hist[1][iv.y], signed_val(x1, sv.y));
        unsafeAtomicAdd(&hist[1][iv.z], signed_val(x1, sv.z));
        unsafeAtomicAdd(&hist[1][iv.w], signed_val(x1, sv.w));
    }
    __syncthreads();
    float* o = out + (size_t)b0 * P_DIM;
    for (int p = threadIdx.x; p < P_DIM; p += 1024) {
        unsafeAtomicAdd(&o[p],         hist[0][p]);
        unsafeAtomicAdd(&o[P_DIM + p], hist[1][p]);
    }
}

extern "C" void kernel_launch(void* const* d_in, const int* in_sizes, int n_in,
                              void* d_out, int out_size, void* d_ws, size_t ws_size,
                              hipStream_t stream) {
    const float* x   = (const float*)d_in[0];
    const int*   idx = (const int*)d_in[1];
    const int*   sgn = (const int*)d_in[2];
    float* out = (float*)d_out;

    if (ws_size >= WS_NEED) {
        char* ws = (char*)d_ws;
        unsigned short* pk  = (unsigned short*)(ws + PK_OFF);
        unsigned short* xTb = (unsigned short*)(ws + XT_OFF);
        float* part = (float*)(ws + PART_OFF);

        k_pack<<<D_DIM / 256, 256, 0, stream>>>(idx, sgn, pk);
        k_transpose<<<D_DIM / 64, 256, 0, stream>>>(x, xTb);
        k_scan<<<SCAN_BLOCKS, WPB * 64, 0, stream>>>(pk, xTb, part);
        k_reduce<<<NPR, 256, 0, stream>>>(part, out);
    } else {
        hipMemsetAsync(d_out, 0, (size_t)out_size * sizeof(float), stream);
        dim3 grid(16, 32);
        sjlt_hist_fb<<<grid, 1024, 0, stream>>>(x, idx, sgn, out);
    }
}

// Round 7
// 122.254 us; speedup vs baseline: 2.8342x; 1.3143x over previous
//
#include <hip/hip_runtime.h>
#include <hip/hip_bf16.h>
#include <hip/hip_fp16.h>

// SJLT projection: out[b, idx[d,c]] += x[b,d] * (2*sign[d,c]-1)
// B=64, D=262144, C=4, P=4096
//
// R7 = R6 with the sign bug fixed. R6 post-mortem: absmax was 154 = exactly
// 2*max|ref| -> output was the exact negative. gval() XORs the fp32 sign bit
// with entry bit31; R6 stored bit31 = sv, but sv=1 means +x (2s-1). Fix:
// bit31 = sv ^ 1 (flip exactly when sv=0).
//
// Design (R6): block-cooperative scan: 4 waves own 4 adjacent pranges; each
// wave scans 1/4 of the d-slice and bins hits into per-(target,scanner) LDS
// queues (4 ballots/step, race-free, no atomics). Process: groups of 4
// entries, 4 independent bf16 gathers in flight, 6-pair dup-merge, plain
// LDS RMW on a wave-private [64p][64b] f32 histogram. fp16 partials.

constexpr int B_DIM = 64;
constexpr int D_DIM = 262144;
constexpr int P_DIM = 4096;

constexpr int PR_W   = 64;               // p-slots per wave
constexpr int NPR    = P_DIM / PR_W;     // 64 p-ranges
constexpr int NDS    = 32;               // d-slices
constexpr int SLICE  = D_DIM / NDS;      // 8192
constexpr int WPB    = 4;                // waves per block (= pranges per block)
constexpr int SUB    = SLICE / WPB;      // 2048 d scanned per wave
constexpr int SCAN_BLOCKS = (NPR / WPB) * NDS;  // 512
constexpr int QCAP   = 224;              // per (target,scanner): mean 128, sd 11 -> 8.5 sigma

// ---- ws layout ----
constexpr size_t PK_OFF   = 0;
constexpr size_t PK_BYTES = (size_t)D_DIM * 4 * sizeof(unsigned short);          // 2 MB
constexpr size_t XT_OFF   = PK_OFF + PK_BYTES;
constexpr size_t XT_BYTES = (size_t)D_DIM * B_DIM * sizeof(unsigned short);      // 33.5 MB
constexpr size_t PART_OFF = XT_OFF + XT_BYTES;
constexpr size_t PART_BYTES = (size_t)NPR * NDS * PR_W * B_DIM * sizeof(__half); // 16.8 MB
constexpr size_t WS_NEED  = PART_OFF + PART_BYTES;                               // ~53 MB

// ---------------- K1: pack idx+sign into ushort ----------------
__global__ __launch_bounds__(256) void k_pack(
    const int* __restrict__ idx, const int* __restrict__ sgn,
    unsigned short* __restrict__ pk) {
    const int d = blockIdx.x * 256 + threadIdx.x;
    const int4 iv = reinterpret_cast<const int4*>(idx)[d];
    const int4 sv = reinterpret_cast<const int4*>(sgn)[d];
    ushort4 o;
    o.x = (unsigned short)((iv.x & 4095) | (sv.x << 15));
    o.y = (unsigned short)((iv.y & 4095) | (sv.y << 15));
    o.z = (unsigned short)((iv.z & 4095) | (sv.z << 15));
    o.w = (unsigned short)((iv.w & 4095) | (sv.w << 15));
    reinterpret_cast<ushort4*>(pk)[d] = o;
}

// ---------------- K2: transpose x[64][D] -> xTb[D][64] (bf16) ----------------
__device__ __forceinline__ unsigned short f32_to_bf16_rne(float f) {
    unsigned u = __float_as_uint(f);
    u += 0x7FFFu + ((u >> 16) & 1u);
    return (unsigned short)(u >> 16);
}

__global__ __launch_bounds__(256) void k_transpose(
    const float* __restrict__ x, unsigned short* __restrict__ xTb) {
    __shared__ float tile[64 * 65];
    const int d0 = blockIdx.x * 64;
    const int t = threadIdx.x;
    const int lane = t & 63;
    #pragma unroll
    for (int k = 0; k < 16; ++k) {
        const int b = k * 4 + (t >> 6);
        tile[lane * 65 + b] = x[(size_t)b * D_DIM + d0 + lane];
    }
    __syncthreads();
    #pragma unroll
    for (int k = 0; k < 16; ++k) {
        const int dr = k * 4 + (t >> 6);
        xTb[(size_t)(d0 + dr) * B_DIM + lane] = f32_to_bf16_rne(tile[dr * 65 + lane]);
    }
}

// ---------------- K3: cooperative scan + process ----------------
// entry: bits 0-19 = byte row offset (dloc*128), 20-25 = poff,
//        bit 31 = (sv ^ 1)  -> gval XOR-negates exactly when sv==0.
__device__ __forceinline__ float gval(const unsigned short* __restrict__ xs,
                                      unsigned e, int lane) {
    const unsigned short xv = xs[((e & 0xFFFFFu) >> 1) + (unsigned)lane];
    return __uint_as_float(((unsigned)xv << 16) ^ (e & 0x80000000u));
}

__global__ __launch_bounds__(WPB * 64) void k_scan(
    const unsigned short* __restrict__ pk,
    const unsigned short* __restrict__ xTb,
    __half* __restrict__ part) {
    __shared__ float hist[WPB][PR_W * 64];      // 64 KB
    __shared__ unsigned q[WPB][WPB][QCAP];      // [target][scanner] 14.3 KB
    __shared__ int qcnt[WPB][WPB];

    const int w    = threadIdx.x >> 6;
    const int lane = threadIdx.x & 63;
    const int dslice  = blockIdx.x & (NDS - 1);  // same-slice blocks -> same XCD
    const int prgroup = blockIdx.x >> 5;
    const unsigned p0 = (unsigned)(prgroup * (WPB * PR_W));  // block's 256-wide p base
    const int dbase   = dslice * SLICE;

    float* h = hist[w];
    #pragma unroll
    for (int k = 0; k < PR_W; ++k) h[k * 64 + lane] = 0.0f;

    // --- scan phase: wave w scans slice-local d in [w*SUB, (w+1)*SUB) ---
    const ushort4* pk4 = reinterpret_cast<const ushort4*>(pk);
    const unsigned long long lmask = (1ull << lane) - 1ull;
    int c0 = 0, c1 = 0, c2 = 0, c3 = 0;
    for (int step = 0; step < SUB / 64; ++step) {   // 32 steps
        const int dloc = w * SUB + step * 64 + lane;
        const ushort4 v = pk4[dbase + dloc];
        #pragma unroll
        for (int c = 0; c < 4; ++c) {
            const unsigned u = (c == 0) ? v.x : (c == 1) ? v.y : (c == 2) ? v.z : v.w;
            const unsigned off = (u & 4095u) - p0;           // unsigned wrap
            const bool hit = off < (unsigned)(WPB * PR_W);
            const unsigned t = hit ? (off >> 6) : 0xFFu;
            const unsigned e = ((unsigned)dloc << 7) | ((off & 63u) << 20)
                             | (((u >> 15) ^ 1u) << 31);     // FIXED: bit31 = sv^1
            const unsigned long long m0 = __ballot(t == 0u);
            const unsigned long long m1 = __ballot(t == 1u);
            const unsigned long long m2 = __ballot(t == 2u);
            const unsigned long long m3 = __ballot(t == 3u);
            if (hit) {
                const unsigned long long mt = (t == 0) ? m0 : (t == 1) ? m1
                                            : (t == 2) ? m2 : m3;
                const int base = (t == 0) ? c0 : (t == 1) ? c1 : (t == 2) ? c2 : c3;
                const int pos = base + __popcll(mt & lmask);
                if (pos < QCAP) q[t][w][pos] = e;
            }
            c0 += __popcll(m0); c1 += __popcll(m1);
            c2 += __popcll(m2); c3 += __popcll(m3);
        }
    }
    if (lane == 0) {
        qcnt[0][w] = c0 < QCAP ? c0 : QCAP;
        qcnt[1][w] = c1 < QCAP ? c1 : QCAP;
        qcnt[2][w] = c2 < QCAP ? c2 : QCAP;
        qcnt[3][w] = c3 < QCAP ? c3 : QCAP;
    }
    __syncthreads();

    // --- process phase: wave w owns prange = prgroup*WPB + w ---
    const unsigned short* xs = xTb + (size_t)dbase * B_DIM;
    for (int s = 0; s < WPB; ++s) {
        const int n = qcnt[w][s];
        const unsigned* qs = q[w][s];
        int i = 0;
        for (; i + 4 <= n; i += 4) {
            const unsigned e0 = qs[i], e1 = qs[i + 1], e2 = qs[i + 2], e3 = qs[i + 3];
            float v0 = gval(xs, e0, lane), v1 = gval(xs, e1, lane);
            float v2 = gval(xs, e2, lane), v3 = gval(xs, e3, lane);
            const unsigned a0 = ((e0 >> 14) & 0xFC0u) | (unsigned)lane;
            const unsigned a1 = ((e1 >> 14) & 0xFC0u) | (unsigned)lane;
            const unsigned a2 = ((e2 >> 14) & 0xFC0u) | (unsigned)lane;
            const unsigned a3 = ((e3 >> 14) & 0xFC0u) | (unsigned)lane;
            // 6-pair duplicate merge (addresses equal iff poffs equal)
            bool d01 = (a0 == a1), d02 = (a0 == a2), d03 = (a0 == a3);
            bool d12 = (a1 == a2), d13 = (a1 == a3), d23 = (a2 == a3);
            v1 += d01 ? v0 : 0.0f;  v0 = d01 ? 0.0f : v0;
            v2 += d02 ? v0 : 0.0f;  v0 = d02 ? 0.0f : v0;
            v2 += d12 ? v1 : 0.0f;  v1 = d12 ? 0.0f : v1;
            v3 += d03 ? v0 : 0.0f;  v0 = d03 ? 0.0f : v0;
            v3 += d13 ? v1 : 0.0f;  v1 = d13 ? 0.0f : v1;
            v3 += d23 ? v2 : 0.0f;  v2 = d23 ? 0.0f : v2;
            const float h0 = h[a0], h1 = h[a1], h2 = h[a2], h3 = h[a3];
            h[a0] = h0 + v0; h[a1] = h1 + v1; h[a2] = h2 + v2; h[a3] = h3 + v3;
        }
        for (; i < n; ++i) {   // tail: serial RMW
            const unsigned e = qs[i];
            h[((e >> 14) & 0xFC0u) | (unsigned)lane] += gval(xs, e, lane);
        }
    }

    // partials (fp16): part[(prange*NDS+dslice)*PR_W*B + poff*B + b]
    __half* wp = part + ((size_t)((prgroup * WPB + w) * NDS + dslice)) * (PR_W * B_DIM);
    #pragma unroll
    for (int po = 0; po < PR_W; ++po)
        wp[po * 64 + lane] = __float2half(h[po * 64 + lane]);
}

// ---------------- K4: reduce partials -> out ----------------
__global__ __launch_bounds__(256) void k_reduce(
    const __half* __restrict__ part, float* __restrict__ out) {
    __shared__ float acc[16 * 65];
    const int pr = blockIdx.x;       // p-range 0..63
    const int pq = blockIdx.y;       // poff quarter 0..3
    const int t  = threadIdx.x;

    for (int i = t; i < 16 * 65; i += 256) acc[i] = 0.0f;
    __syncthreads();

    for (int ds = 0; ds < NDS; ++ds) {
        const __half* src = part + ((size_t)(pr * NDS + ds)) * (PR_W * B_DIM)
                          + pq * 16 * B_DIM;
        #pragma unroll
        for (int k = 0; k < 4; ++k) {
            const int idx = k * 256 + t;            // po_local*64 + b
            acc[(idx >> 6) * 65 + (idx & 63)] += __half2float(src[idx]);
        }
    }
    __syncthreads();

    #pragma unroll
    for (int k = 0; k < 4; ++k) {
        const int idx = k * 256 + t;
        const int po = idx & 15, b = idx >> 4;
        out[(size_t)b * P_DIM + pr * PR_W + pq * 16 + po] = acc[po * 65 + b];
    }
}

// ---------------- fallback: LDS-atomic histogram ----------------
__device__ __forceinline__ float signed_val(float x, int s) {
    return __uint_as_float(__float_as_uint(x) ^ (((unsigned)(s ^ 1)) << 31));
}

__global__ __launch_bounds__(1024) void sjlt_hist_fb(
    const float* __restrict__ x, const int* __restrict__ idx,
    const int* __restrict__ sgn, float* __restrict__ out) {
    __shared__ float hist[2][P_DIM];
    for (int i = threadIdx.x; i < 2 * P_DIM; i += 1024) (&hist[0][0])[i] = 0.0f;
    __syncthreads();
    const int chunk = blockIdx.x, bg = blockIdx.y;
    const int d0 = chunk * (D_DIM / 16), b0 = bg * 2;
    const float* xr0 = x + (size_t)b0 * D_DIM + d0;
    const float* xr1 = xr0 + D_DIM;
    const int4* iv4 = reinterpret_cast<const int4*>(idx) + d0;
    const int4* sv4 = reinterpret_cast<const int4*>(sgn) + d0;
    for (int t = threadIdx.x; t < D_DIM / 16; t += 1024) {
        const int4 iv = iv4[t]; const int4 sv = sv4[t];
        const float x0 = xr0[t], x1 = xr1[t];
        unsafeAtomicAdd(&hist[0][iv.x], signed_val(x0, sv.x));
        unsafeAtomicAdd(&hist[0][iv.y], signed_val(x0, sv.y));
        unsafeAtomicAdd(&hist[0][iv.z], signed_val(x0, sv.z));
        unsafeAtomicAdd(&hist[0][iv.w], signed_val(x0, sv.w));
        unsafeAtomicAdd(&hist[1][iv.x], signed_val(x1, sv.x));
        unsafeAtomicAdd(&hist[1][iv.y], signed_val(x1, sv.y));
        unsafeAtomicAdd(&hist[1][iv.z], signed_val(x1, sv.z));
        unsafeAtomicAdd(&hist[1][iv.w], signed_val(x1, sv.w));
    }
    __syncthreads();
    float* o = out + (size_t)b0 * P_DIM;
    for (int p = threadIdx.x; p < P_DIM; p += 1024) {
        unsafeAtomicAdd(&o[p],         hist[0][p]);
        unsafeAtomicAdd(&o[P_DIM + p], hist[1][p]);
    }
}

extern "C" void kernel_launch(void* const* d_in, const int* in_sizes, int n_in,
                              void* d_out, int out_size, void* d_ws, size_t ws_size,
                              hipStream_t stream) {
    const float* x   = (const float*)d_in[0];
    const int*   idx = (const int*)d_in[1];
    const int*   sgn = (const int*)d_in[2];
    float* out = (float*)d_out;

    if (ws_size >= WS_NEED) {
        char* ws = (char*)d_ws;
        unsigned short* pk  = (unsigned short*)(ws + PK_OFF);
        unsigned short* xTb = (unsigned short*)(ws + XT_OFF);
        __half* part = (__half*)(ws + PART_OFF);

        k_pack<<<D_DIM / 256, 256, 0, stream>>>(idx, sgn, pk);
        k_transpose<<<D_DIM / 64, 256, 0, stream>>>(x, xTb);
        k_scan<<<SCAN_BLOCKS, WPB * 64, 0, stream>>>(pk, xTb, part);
        k_reduce<<<dim3(NPR, 4), 256, 0, stream>>>(part, out);
    } else {
        hipMemsetAsync(d_out, 0, (size_t)out_size * sizeof(float), stream);
        dim3 grid(16, 32);
        sjlt_hist_fb<<<grid, 1024, 0, stream>>>(x, idx, sgn, out);
    }
}

// Round 9
// 113.198 us; speedup vs baseline: 3.0609x; 1.0800x over previous
//
#include <hip/hip_runtime.h>
#include <hip/hip_bf16.h>
#include <hip/hip_fp16.h>

// SJLT projection: out[b, idx[d,c]] += x[b,d] * (2*sign[d,c]-1)
// B=64, D=262144, C=4, P=4096
//
// R9 = R8 with the collision path fixed. R8 post-mortem (absmax 10.75):
// the rare poL==poH case was "serialized" as
//   if(C) X; else { if(!hi) X; if(hi) X; }   with identical X
// which LLVM legally merges to plain X (lane-local memory model) -> lanes
// li and li+32 RMW the same LDS word in one instruction, one add lost per
// word across the whole 64-b row (~8K events -> absmax ~10). Fix: on
// (uniform, scalar-detected) collision, cross-half __shfl brings the hi
// half's packed value to the lo half, lo lanes do ONE RMW with the sum.
// No ordering for the compiler to break.
//
// Design recap (R8): cooperative scan (4 waves own 4 pranges, bin into
// per-(target,scanner) queues, race-free, no atomics); process phase
// scalarized via readfirstlane (entries wave-uniform); lane owns a b-pair
// (dword = 2 bf16), hist is packed f16x2 [64po][32w] = 8 KB/wave; partials
// fp16; NOT ds_add_f32 (R2/R3: LDS atomics ~3cyc/lane wall).

constexpr int B_DIM = 64;
constexpr int D_DIM = 262144;
constexpr int P_DIM = 4096;

constexpr int PR_W   = 64;               // p-slots per wave
constexpr int NPR    = P_DIM / PR_W;     // 64 p-ranges
constexpr int NDS    = 32;               // d-slices
constexpr int SLICE  = D_DIM / NDS;      // 8192
constexpr int WPB    = 4;                // waves per block (= pranges per block)
constexpr int SUB    = SLICE / WPB;      // 2048 d scanned per wave
constexpr int SCAN_BLOCKS = (NPR / WPB) * NDS;  // 512
constexpr int QCAP   = 224;              // per (target,scanner): mean 128, sd 11 -> 8.5 sigma

// ---- ws layout ----
constexpr size_t PK_OFF   = 0;
constexpr size_t PK_BYTES = (size_t)D_DIM * 4 * sizeof(unsigned short);          // 2 MB
constexpr size_t XT_OFF   = PK_OFF + PK_BYTES;
constexpr size_t XT_BYTES = (size_t)D_DIM * B_DIM * sizeof(unsigned short);      // 33.5 MB
constexpr size_t PART_OFF = XT_OFF + XT_BYTES;
constexpr size_t PART_BYTES = (size_t)NPR * NDS * PR_W * B_DIM * sizeof(__half); // 16.8 MB
constexpr size_t WS_NEED  = PART_OFF + PART_BYTES;                               // ~53 MB

// ---------------- K1: pack idx+sign into ushort ----------------
__global__ __launch_bounds__(256) void k_pack(
    const int* __restrict__ idx, const int* __restrict__ sgn,
    unsigned short* __restrict__ pk) {
    const int d = blockIdx.x * 256 + threadIdx.x;
    const int4 iv = reinterpret_cast<const int4*>(idx)[d];
    const int4 sv = reinterpret_cast<const int4*>(sgn)[d];
    ushort4 o;
    o.x = (unsigned short)((iv.x & 4095) | (sv.x << 15));
    o.y = (unsigned short)((iv.y & 4095) | (sv.y << 15));
    o.z = (unsigned short)((iv.z & 4095) | (sv.z << 15));
    o.w = (unsigned short)((iv.w & 4095) | (sv.w << 15));
    reinterpret_cast<ushort4*>(pk)[d] = o;
}

// ---------------- K2: transpose x[64][D] -> xTb[D][64] (bf16) ----------------
__device__ __forceinline__ unsigned short f32_to_bf16_rne(float f) {
    unsigned u = __float_as_uint(f);
    u += 0x7FFFu + ((u >> 16) & 1u);
    return (unsigned short)(u >> 16);
}

__global__ __launch_bounds__(256) void k_transpose(
    const float* __restrict__ x, unsigned short* __restrict__ xTb) {
    __shared__ float tile[64 * 65];
    const int d0 = blockIdx.x * 64;
    const int t = threadIdx.x;
    const int lane = t & 63;
    #pragma unroll
    for (int k = 0; k < 16; ++k) {
        const int b = k * 4 + (t >> 6);
        tile[lane * 65 + b] = x[(size_t)b * D_DIM + d0 + lane];
    }
    __syncthreads();
    #pragma unroll
    for (int k = 0; k < 16; ++k) {
        const int dr = k * 4 + (t >> 6);
        xTb[(size_t)(d0 + dr) * B_DIM + lane] = f32_to_bf16_rne(tile[dr * 65 + lane]);
    }
}

// ---------------- K3: cooperative scan + scalarized paired process ----------
// entry: bits 0-19 = byte row offset (dloc*128), 20-25 = poff,
//        bit 31 = (sv ^ 1)  -> negate exactly when sv==0.
__global__ __launch_bounds__(WPB * 64) void k_scan(
    const unsigned short* __restrict__ pk,
    const unsigned short* __restrict__ xTb,
    __half* __restrict__ part) {
    __shared__ __half2 hist[WPB][PR_W * 32];          // 4 x 8 KB = 32 KB (f16x2)
    __shared__ alignas(16) unsigned q[WPB][WPB][QCAP]; // [target][scanner] 14.3 KB
    __shared__ int qcnt[WPB][WPB];

    const int w    = threadIdx.x >> 6;
    const int lane = threadIdx.x & 63;
    const int dslice  = blockIdx.x & (NDS - 1);  // same-slice blocks -> same XCD
    const int prgroup = blockIdx.x >> 5;
    const unsigned p0 = (unsigned)(prgroup * (WPB * PR_W));  // block's 256-wide p base
    const int dbase   = dslice * SLICE;

    __half2* h2 = hist[w];
    {
        unsigned* h32 = reinterpret_cast<unsigned*>(h2);
        #pragma unroll
        for (int k = 0; k < 32; ++k) h32[k * 64 + lane] = 0u;
    }

    // --- scan phase: wave w scans slice-local d in [w*SUB, (w+1)*SUB) ---
    const ushort4* pk4 = reinterpret_cast<const ushort4*>(pk);
    const unsigned long long lmask = (1ull << lane) - 1ull;
    int c0 = 0, c1 = 0, c2 = 0, c3 = 0;
    for (int step = 0; step < SUB / 64; ++step) {   // 32 steps
        const int dloc = w * SUB + step * 64 + lane;
        const ushort4 v = pk4[dbase + dloc];
        #pragma unroll
        for (int c = 0; c < 4; ++c) {
            const unsigned u = (c == 0) ? v.x : (c == 1) ? v.y : (c == 2) ? v.z : v.w;
            const unsigned off = (u & 4095u) - p0;           // unsigned wrap
            const bool hit = off < (unsigned)(WPB * PR_W);
            const unsigned t = hit ? (off >> 6) : 0xFFu;
            const unsigned e = ((unsigned)dloc << 7) | ((off & 63u) << 20)
                             | (((u >> 15) ^ 1u) << 31);
            const unsigned long long m0 = __ballot(t == 0u);
            const unsigned long long m1 = __ballot(t == 1u);
            const unsigned long long m2 = __ballot(t == 2u);
            const unsigned long long m3 = __ballot(t == 3u);
            if (hit) {
                const unsigned long long mt = (t == 0) ? m0 : (t == 1) ? m1
                                            : (t == 2) ? m2 : m3;
                const int base = (t == 0) ? c0 : (t == 1) ? c1 : (t == 2) ? c2 : c3;
                const int pos = base + __popcll(mt & lmask);
                if (pos < QCAP) q[t][w][pos] = e;
            }
            c0 += __popcll(m0); c1 += __popcll(m1);
            c2 += __popcll(m2); c3 += __popcll(m3);
        }
    }
    if (lane == 0) {
        qcnt[0][w] = c0 < QCAP ? c0 : QCAP;
        qcnt[1][w] = c1 < QCAP ? c1 : QCAP;
        qcnt[2][w] = c2 < QCAP ? c2 : QCAP;
        qcnt[3][w] = c3 < QCAP ? c3 : QCAP;
    }
    __syncthreads();

    // --- process phase: wave w owns prange = prgroup*WPB + w ---
    const char* xs_c = reinterpret_cast<const char*>(xTb + (size_t)dbase * B_DIM);
    const unsigned li4 = (unsigned)(lane & 31) * 4u;
    const bool hi = lane >= 32;

    // one pair-op: two uniform entries (eL->lanes 0-31, eH->lanes 32-63),
    // dv = this lane's gathered dword (2 bf16 for b = 2*li, 2*li+1)
    auto pair_rmw = [&](unsigned eL, unsigned eH, unsigned dv) {
        const unsigned poL = (eL >> 20) & 63u, poH = (eH >> 20) & 63u;
        const unsigned smL = (eL >> 31) ? 0x80008000u : 0u;
        const unsigned smH = (eH >> 31) ? 0x80008000u : 0u;
        const float flo = __uint_as_float(dv << 16);
        const float fhh = __uint_as_float(dv & 0xFFFF0000u);
        unsigned pkb = __builtin_bit_cast(unsigned, __floats2half2_rn(flo, fhh));
        pkb ^= hi ? smH : smL;
        const unsigned a = (hi ? poH : poL) * 32u + (unsigned)(lane & 31);
        if (poL != poH) {                       // uniform (scalar) branch
            const __half2 v2 = __builtin_bit_cast(__half2, pkb);
            h2[a] = __hadd2(h2[a], v2);
        } else {
            // rare collision (both entries -> same row): combine across
            // halves in-register, single RMW by lo half. Nothing for the
            // compiler to merge/reorder.
            const unsigned other = (unsigned)__shfl((int)pkb, (lane & 31) + 32);
            if (!hi) {
                const __half2 vsum = __hadd2(__builtin_bit_cast(__half2, pkb),
                                             __builtin_bit_cast(__half2, other));
                h2[a] = __hadd2(h2[a], vsum);
            }
        }
    };

    for (int s = 0; s < WPB; ++s) {
        const int n = qcnt[w][s];
        const unsigned* qs = q[w][s];
        const uint4* qs4 = reinterpret_cast<const uint4*>(qs);
        int i = 0;
        for (; i + 8 <= n; i += 8) {            // 4 pair-ops, 4 gathers in flight
            const uint4 Ea = qs4[i >> 2];
            const uint4 Eb = qs4[(i >> 2) + 1];
            const unsigned e0 = __builtin_amdgcn_readfirstlane(Ea.x);
            const unsigned e1 = __builtin_amdgcn_readfirstlane(Ea.y);
            const unsigned e2 = __builtin_amdgcn_readfirstlane(Ea.z);
            const unsigned e3 = __builtin_amdgcn_readfirstlane(Ea.w);
            const unsigned e4 = __builtin_amdgcn_readfirstlane(Eb.x);
            const unsigned e5 = __builtin_amdgcn_readfirstlane(Eb.y);
            const unsigned e6 = __builtin_amdgcn_readfirstlane(Eb.z);
            const unsigned e7 = __builtin_amdgcn_readfirstlane(Eb.w);
            const unsigned va0 = (hi ? (e1 & 0xFFFFFu) : (e0 & 0xFFFFFu)) + li4;
            const unsigned va1 = (hi ? (e3 & 0xFFFFFu) : (e2 & 0xFFFFFu)) + li4;
            const unsigned va2 = (hi ? (e5 & 0xFFFFFu) : (e4 & 0xFFFFFu)) + li4;
            const unsigned va3 = (hi ? (e7 & 0xFFFFFu) : (e6 & 0xFFFFFu)) + li4;
            const unsigned d0 = *reinterpret_cast<const unsigned*>(xs_c + va0);
            const unsigned d1 = *reinterpret_cast<const unsigned*>(xs_c + va1);
            const unsigned d2 = *reinterpret_cast<const unsigned*>(xs_c + va2);
            const unsigned d3 = *reinterpret_cast<const unsigned*>(xs_c + va3);
            pair_rmw(e0, e1, d0);
            pair_rmw(e2, e3, d1);
            pair_rmw(e4, e5, d2);
            pair_rmw(e6, e7, d3);
        }
        for (; i + 2 <= n; i += 2) {
            const unsigned e0 = __builtin_amdgcn_readfirstlane(qs[i]);
            const unsigned e1 = __builtin_amdgcn_readfirstlane(qs[i + 1]);
            const unsigned va = (hi ? (e1 & 0xFFFFFu) : (e0 & 0xFFFFFu)) + li4;
            const unsigned dv = *reinterpret_cast<const unsigned*>(xs_c + va);
            pair_rmw(e0, e1, dv);
        }
        if (i < n) {                            // odd tail: half-wave op
            const unsigned e0 = __builtin_amdgcn_readfirstlane(qs[i]);
            if (!hi) {
                const unsigned va = (e0 & 0xFFFFFu) + li4;
                const unsigned dv = *reinterpret_cast<const unsigned*>(xs_c + va);
                const float flo = __uint_as_float(dv << 16);
                const float fhh = __uint_as_float(dv & 0xFFFF0000u);
                unsigned pkb = __builtin_bit_cast(unsigned, __floats2half2_rn(flo, fhh));
                pkb ^= (e0 >> 31) ? 0x80008000u : 0u;
                const __half2 v2 = __builtin_bit_cast(__half2, pkb);
                const unsigned a = ((e0 >> 20) & 63u) * 32u + (unsigned)(lane & 31);
                h2[a] = __hadd2(h2[a], v2);
            }
        }
    }

    // partials (fp16, layout poff*64 + b): copy as dwords
    unsigned* wp32 = reinterpret_cast<unsigned*>(
        part + ((size_t)((prgroup * WPB + w) * NDS + dslice)) * (PR_W * B_DIM));
    const unsigned* h32 = reinterpret_cast<const unsigned*>(h2);
    #pragma unroll
    for (int k = 0; k < 32; ++k)
        wp32[k * 64 + lane] = h32[k * 64 + lane];
}

// ---------------- K4: reduce partials -> out ----------------
__global__ __launch_bounds__(256) void k_reduce(
    const __half* __restrict__ part, float* __restrict__ out) {
    __shared__ float acc[16 * 65];
    const int pr = blockIdx.x;       // p-range 0..63
    const int pq = blockIdx.y;       // poff quarter 0..3
    const int t  = threadIdx.x;

    for (int i = t; i < 16 * 65; i += 256) acc[i] = 0.0f;
    __syncthreads();

    for (int ds = 0; ds < NDS; ++ds) {
        const __half* src = part + ((size_t)(pr * NDS + ds)) * (PR_W * B_DIM)
                          + pq * 16 * B_DIM;
        #pragma unroll
        for (int k = 0; k < 4; ++k) {
            const int idx = k * 256 + t;            // po_local*64 + b
            acc[(idx >> 6) * 65 + (idx & 63)] += __half2float(src[idx]);
        }
    }
    __syncthreads();

    #pragma unroll
    for (int k = 0; k < 4; ++k) {
        const int idx = k * 256 + t;
        const int po = idx & 15, b = idx >> 4;
        out[(size_t)b * P_DIM + pr * PR_W + pq * 16 + po] = acc[po * 65 + b];
    }
}

// ---------------- fallback: LDS-atomic histogram ----------------
__device__ __forceinline__ float signed_val(float x, int s) {
    return __uint_as_float(__float_as_uint(x) ^ (((unsigned)(s ^ 1)) << 31));
}

__global__ __launch_bounds__(1024) void sjlt_hist_fb(
    const float* __restrict__ x, const int* __restrict__ idx,
    const int* __restrict__ sgn, float* __restrict__ out) {
    __shared__ float hist[2][P_DIM];
    for (int i = threadIdx.x; i < 2 * P_DIM; i += 1024) (&hist[0][0])[i] = 0.0f;
    __syncthreads();
    const int chunk = blockIdx.x, bg = blockIdx.y;
    const int d0 = chunk * (D_DIM / 16), b0 = bg * 2;
    const float* xr0 = x + (size_t)b0 * D_DIM + d0;
    const float* xr1 = xr0 + D_DIM;
    const int4* iv4 = reinterpret_cast<const int4*>(idx) + d0;
    const int4* sv4 = reinterpret_cast<const int4*>(sgn) + d0;
    for (int t = threadIdx.x; t < D_DIM / 16; t += 1024) {
        const int4 iv = iv4[t]; const int4 sv = sv4[t];
        const float x0 = xr0[t], x1 = xr1[t];
        unsafeAtomicAdd(&hist[0][iv.x], signed_val(x0, sv.x));
        unsafeAtomicAdd(&hist[0][iv.y], signed_val(x0, sv.y));
        unsafeAtomicAdd(&hist[0][iv.z], signed_val(x0, sv.z));
        unsafeAtomicAdd(&hist[0][iv.w], signed_val(x0, sv.w));
        unsafeAtomicAdd(&hist[1][iv.x], signed_val(x1, sv.x));
        unsafeAtomicAdd(&hist[1][iv.y], signed_val(x1, sv.y));
        unsafeAtomicAdd(&hist[1][iv.z], signed_val(x1, sv.z));
        unsafeAtomicAdd(&hist[1][iv.w], signed_val(x1, sv.w));
    }
    __syncthreads();
    float* o = out + (size_t)b0 * P_DIM;
    for (int p = threadIdx.x; p < P_DIM; p += 1024) {
        unsafeAtomicAdd(&o[p],         hist[0][p]);
        unsafeAtomicAdd(&o[P_DIM + p], hist[1][p]);
    }
}

extern "C" void kernel_launch(void* const* d_in, const int* in_sizes, int n_in,
                              void* d_out, int out_size, void* d_ws, size_t ws_size,
                              hipStream_t stream) {
    const float* x   = (const float*)d_in[0];
    const int*   idx = (const int*)d_in[1];
    const int*   sgn = (const int*)d_in[2];
    float* out = (float*)d_out;

    if (ws_size >= WS_NEED) {
        char* ws = (char*)d_ws;
        unsigned short* pk  = (unsigned short*)(ws + PK_OFF);
        unsigned short* xTb = (unsigned short*)(ws + XT_OFF);
        __half* part = (__half*)(ws + PART_OFF);

        k_pack<<<D_DIM / 256, 256, 0, stream>>>(idx, sgn, pk);
        k_transpose<<<D_DIM / 64, 256, 0, stream>>>(x, xTb);
        k_scan<<<SCAN_BLOCKS, WPB * 64, 0, stream>>>(pk, xTb, part);
        k_reduce<<<dim3(NPR, 4), 256, 0, stream>>>(part, out);
    } else {
        hipMemsetAsync(d_out, 0, (size_t)out_size * sizeof(float), stream);
        dim3 grid(16, 32);
        sjlt_hist_fb<<<grid, 1024, 0, stream>>>(x, idx, sgn, out);
    }
}

// Round 10
// 95.201 us; speedup vs baseline: 3.6396x; 1.1890x over previous
//
#include <hip/hip_runtime.h>
#include <hip/hip_bf16.h>
#include <hip/hip_fp16.h>

// SJLT projection: out[b, idx[d,c]] += x[b,d] * (2*sign[d,c]-1)
// B=64, D=262144, C=4, P=4096
//
// R10. R9 post-mortem: k_scan 83.5us, occupancy GRID-capped at 2 blocks/CU
// (512 blocks exactly), scan still 16x-redundant. Changes:
//   - WPB=8 (8 waves / 8 pranges per block): scan redundancy 16x->8x,
//     per-wave scan work 4x smaller (SUB=512).
//   - NDS=64 (grid stays 512 = 2/CU) and u16 queue entries (dloc is
//     scanner-local 9b + poff 6b + sign 1b): LDS = 64K hist + 12K q
//     = 76.8 KB -> 2 blocks/CU resident = 16 waves/CU (2x occupancy).
//   - binning via 8 ballots; counts in SGPRs (select tree), zero atomics,
//     deterministic. Process = R9's proven scalarized pair-RMW.
//   - dslice = blockIdx&63: the 8 blocks sharing one 512KB xTb slice sit
//     on one XCD (stride-64 blockIdx -> same XCD under round-robin).

constexpr int B_DIM = 64;
constexpr int D_DIM = 262144;
constexpr int P_DIM = 4096;

constexpr int PR_W   = 64;               // p-slots per wave
constexpr int NPR    = P_DIM / PR_W;     // 64 p-ranges
constexpr int NDS    = 64;               // d-slices
constexpr int SLICE  = D_DIM / NDS;      // 4096
constexpr int WPB    = 8;                // waves per block (= pranges per block)
constexpr int SUB    = SLICE / WPB;      // 512 d scanned per wave
constexpr int SCAN_BLOCKS = (NPR / WPB) * NDS;  // 8*64 = 512
constexpr int QCAP   = 96;               // per (target,scanner): mean 32, sd 5.6 -> 11 sigma

// ---- ws layout ----
constexpr size_t PK_OFF   = 0;
constexpr size_t PK_BYTES = (size_t)D_DIM * 4 * sizeof(unsigned short);          // 2 MB
constexpr size_t XT_OFF   = PK_OFF + PK_BYTES;
constexpr size_t XT_BYTES = (size_t)D_DIM * B_DIM * sizeof(unsigned short);      // 33.5 MB
constexpr size_t PART_OFF = XT_OFF + XT_BYTES;
constexpr size_t PART_BYTES = (size_t)NPR * NDS * PR_W * B_DIM * sizeof(__half); // 33.5 MB
constexpr size_t WS_NEED  = PART_OFF + PART_BYTES;                               // ~69 MB

// ---------------- K1: pack idx+sign into ushort ----------------
__global__ __launch_bounds__(256) void k_pack(
    const int* __restrict__ idx, const int* __restrict__ sgn,
    unsigned short* __restrict__ pk) {
    const int d = blockIdx.x * 256 + threadIdx.x;
    const int4 iv = reinterpret_cast<const int4*>(idx)[d];
    const int4 sv = reinterpret_cast<const int4*>(sgn)[d];
    ushort4 o;
    o.x = (unsigned short)((iv.x & 4095) | (sv.x << 15));
    o.y = (unsigned short)((iv.y & 4095) | (sv.y << 15));
    o.z = (unsigned short)((iv.z & 4095) | (sv.z << 15));
    o.w = (unsigned short)((iv.w & 4095) | (sv.w << 15));
    reinterpret_cast<ushort4*>(pk)[d] = o;
}

// ---------------- K2: transpose x[64][D] -> xTb[D][64] (bf16) ----------------
__device__ __forceinline__ unsigned short f32_to_bf16_rne(float f) {
    unsigned u = __float_as_uint(f);
    u += 0x7FFFu + ((u >> 16) & 1u);
    return (unsigned short)(u >> 16);
}

__global__ __launch_bounds__(256) void k_transpose(
    const float* __restrict__ x, unsigned short* __restrict__ xTb) {
    __shared__ float tile[64 * 65];
    const int d0 = blockIdx.x * 64;
    const int t = threadIdx.x;
    const int lane = t & 63;
    #pragma unroll
    for (int k = 0; k < 16; ++k) {
        const int b = k * 4 + (t >> 6);
        tile[lane * 65 + b] = x[(size_t)b * D_DIM + d0 + lane];
    }
    __syncthreads();
    #pragma unroll
    for (int k = 0; k < 16; ++k) {
        const int dr = k * 4 + (t >> 6);
        xTb[(size_t)(d0 + dr) * B_DIM + lane] = f32_to_bf16_rne(tile[dr * 65 + lane]);
    }
}

// ---------------- K3: 8-wave cooperative scan + scalarized paired process ---
// u16 entry: bits 0-8 = dloc (scanner-local), 9-14 = poff, 15 = (sv ^ 1).
__global__ __launch_bounds__(WPB * 64, 4) void k_scan(
    const unsigned short* __restrict__ pk,
    const unsigned short* __restrict__ xTb,
    __half* __restrict__ part) {
    __shared__ __half2 hist[WPB][PR_W * 32];                    // 8 x 8 KB = 64 KB
    __shared__ alignas(16) unsigned short q[WPB][WPB][QCAP];    // 12 KB
    __shared__ int qcnt[WPB][WPB];                              // 256 B

    const int w    = threadIdx.x >> 6;
    const int lane = threadIdx.x & 63;
    const int dslice  = blockIdx.x & (NDS - 1);   // stride-64 peers -> same XCD
    const int prgroup = blockIdx.x >> 6;          // 0..7
    const unsigned p0 = (unsigned)(prgroup * (WPB * PR_W));  // 512-wide p base
    const int dbase   = dslice * SLICE;

    __half2* h2 = hist[w];
    {
        unsigned* h32 = reinterpret_cast<unsigned*>(h2);
        #pragma unroll
        for (int k = 0; k < 32; ++k) h32[k * 64 + lane] = 0u;
    }

    // --- scan: wave w scans slice-local d in [w*SUB, (w+1)*SUB) ---
    const ushort4* pk4 = reinterpret_cast<const ushort4*>(pk);
    const unsigned long long lmask = (1ull << lane) - 1ull;
    int c0 = 0, c1 = 0, c2 = 0, c3 = 0, c4 = 0, c5 = 0, c6 = 0, c7 = 0;
    for (int step = 0; step < SUB / 64; ++step) {   // 8 steps
        const int dloc = step * 64 + lane;          // scanner-local (0..511)
        const ushort4 v = pk4[dbase + w * SUB + dloc];
        #pragma unroll
        for (int c = 0; c < 4; ++c) {
            const unsigned u = (c == 0) ? v.x : (c == 1) ? v.y : (c == 2) ? v.z : v.w;
            const unsigned off = (u & 4095u) - p0;            // unsigned wrap
            const bool hit = off < (unsigned)(WPB * PR_W);    // < 512
            const unsigned t = hit ? (off >> 6) : 0xFFu;      // target wave 0..7
            const unsigned long long m0 = __ballot(t == 0u);
            const unsigned long long m1 = __ballot(t == 1u);
            const unsigned long long m2 = __ballot(t == 2u);
            const unsigned long long m3 = __ballot(t == 3u);
            const unsigned long long m4 = __ballot(t == 4u);
            const unsigned long long m5 = __ballot(t == 5u);
            const unsigned long long m6 = __ballot(t == 6u);
            const unsigned long long m7 = __ballot(t == 7u);
            if (hit) {
                const unsigned long long mt =
                    t < 4u ? (t < 2u ? (t == 0u ? m0 : m1) : (t == 2u ? m2 : m3))
                           : (t < 6u ? (t == 4u ? m4 : m5) : (t == 6u ? m6 : m7));
                const int base =
                    t < 4u ? (t < 2u ? (t == 0u ? c0 : c1) : (t == 2u ? c2 : c3))
                           : (t < 6u ? (t == 4u ? c4 : c5) : (t == 6u ? c6 : c7));
                const int pos = base + __popcll(mt & lmask);
                const unsigned e16 = (unsigned)dloc | ((off & 63u) << 9)
                                   | (((u >> 15) ^ 1u) << 15);
                if (pos < QCAP) q[t][w][pos] = (unsigned short)e16;
            }
            c0 += __popcll(m0); c1 += __popcll(m1);
            c2 += __popcll(m2); c3 += __popcll(m3);
            c4 += __popcll(m4); c5 += __popcll(m5);
            c6 += __popcll(m6); c7 += __popcll(m7);
        }
    }
    if (lane == 0) {
        qcnt[0][w] = c0 < QCAP ? c0 : QCAP;
        qcnt[1][w] = c1 < QCAP ? c1 : QCAP;
        qcnt[2][w] = c2 < QCAP ? c2 : QCAP;
        qcnt[3][w] = c3 < QCAP ? c3 : QCAP;
        qcnt[4][w] = c4 < QCAP ? c4 : QCAP;
        qcnt[5][w] = c5 < QCAP ? c5 : QCAP;
        qcnt[6][w] = c6 < QCAP ? c6 : QCAP;
        qcnt[7][w] = c7 < QCAP ? c7 : QCAP;
    }
    __syncthreads();

    // --- process: wave w owns prange = prgroup*8 + w ---
    const char* xs_c = reinterpret_cast<const char*>(xTb + (size_t)dbase * B_DIM);
    const unsigned li4 = (unsigned)(lane & 31) * 4u;
    const bool hi = lane >= 32;

    // one pair-op from packed u32 wrd (lo16 = entry i, hi16 = entry i+1),
    // dv = this lane's gathered dword (2 bf16), sb = s*SUB*128 byte base
    auto pair_rmw = [&](unsigned wrd, unsigned dv) {
        const unsigned poL = (wrd >> 9) & 63u, poH = (wrd >> 25) & 63u;
        const unsigned smL = (wrd & 0x8000u)     ? 0x80008000u : 0u;
        const unsigned smH = (wrd & 0x80000000u) ? 0x80008000u : 0u;
        const float flo = __uint_as_float(dv << 16);
        const float fhh = __uint_as_float(dv & 0xFFFF0000u);
        unsigned pkb = __builtin_bit_cast(unsigned, __floats2half2_rn(flo, fhh));
        pkb ^= hi ? smH : smL;
        const unsigned a = (hi ? poH : poL) * 32u + (unsigned)(lane & 31);
        if (poL != poH) {                       // uniform (scalar) branch
            const __half2 v2 = __builtin_bit_cast(__half2, pkb);
            h2[a] = __hadd2(h2[a], v2);
        } else {
            // rare collision: combine across halves in-register, single RMW
            // by the lo half. Nothing for the compiler to merge/reorder.
            const unsigned other = (unsigned)__shfl((int)pkb, (lane & 31) + 32);
            if (!hi) {
                const __half2 vsum = __hadd2(__builtin_bit_cast(__half2, pkb),
                                             __builtin_bit_cast(__half2, other));
                h2[a] = __hadd2(h2[a], vsum);
            }
        }
    };

    for (int s = 0; s < WPB; ++s) {
        const int n = qcnt[w][s];
        const unsigned short* qs = q[w][s];
        const unsigned sb = (unsigned)(s * SUB) * 128u;   // scanner byte base
        int i = 0;
        for (; i + 8 <= n; i += 8) {            // 4 pair-ops, 4 gathers in flight
            const uint4 E = *reinterpret_cast<const uint4*>(qs + i);
            const unsigned w0 = __builtin_amdgcn_readfirstlane(E.x);
            const unsigned w1 = __builtin_amdgcn_readfirstlane(E.y);
            const unsigned w2 = __builtin_amdgcn_readfirstlane(E.z);
            const unsigned w3 = __builtin_amdgcn_readfirstlane(E.w);
            const unsigned rb0L = sb + (w0 & 511u) * 128u;
            const unsigned rb0H = sb + ((w0 >> 16) & 511u) * 128u;
            const unsigned rb1L = sb + (w1 & 511u) * 128u;
            const unsigned rb1H = sb + ((w1 >> 16) & 511u) * 128u;
            const unsigned rb2L = sb + (w2 & 511u) * 128u;
            const unsigned rb2H = sb + ((w2 >> 16) & 511u) * 128u;
            const unsigned rb3L = sb + (w3 & 511u) * 128u;
            const unsigned rb3H = sb + ((w3 >> 16) & 511u) * 128u;
            const unsigned va0 = (hi ? rb0H : rb0L) + li4;
            const unsigned va1 = (hi ? rb1H : rb1L) + li4;
            const unsigned va2 = (hi ? rb2H : rb2L) + li4;
            const unsigned va3 = (hi ? rb3H : rb3L) + li4;
            const unsigned d0 = *reinterpret_cast<const unsigned*>(xs_c + va0);
            const unsigned d1 = *reinterpret_cast<const unsigned*>(xs_c + va1);
            const unsigned d2 = *reinterpret_cast<const unsigned*>(xs_c + va2);
            const unsigned d3 = *reinterpret_cast<const unsigned*>(xs_c + va3);
            pair_rmw(w0, d0);
            pair_rmw(w1, d1);
            pair_rmw(w2, d2);
            pair_rmw(w3, d3);
        }
        for (; i + 2 <= n; i += 2) {
            const unsigned wrd = __builtin_amdgcn_readfirstlane(
                *reinterpret_cast<const unsigned*>(qs + i));
            const unsigned rbL = sb + (wrd & 511u) * 128u;
            const unsigned rbH = sb + ((wrd >> 16) & 511u) * 128u;
            const unsigned va = (hi ? rbH : rbL) + li4;
            const unsigned dv = *reinterpret_cast<const unsigned*>(xs_c + va);
            pair_rmw(wrd, dv);
        }
        if (i < n) {                            // odd tail: half-wave op
            const unsigned e0 = __builtin_amdgcn_readfirstlane((unsigned)qs[i]);
            if (!hi) {
                const unsigned va = sb + (e0 & 511u) * 128u + li4;
                const unsigned dv = *reinterpret_cast<const unsigned*>(xs_c + va);
                const float flo = __uint_as_float(dv << 16);
                const float fhh = __uint_as_float(dv & 0xFFFF0000u);
                unsigned pkb = __builtin_bit_cast(unsigned, __floats2half2_rn(flo, fhh));
                pkb ^= (e0 & 0x8000u) ? 0x80008000u : 0u;
                const __half2 v2 = __builtin_bit_cast(__half2, pkb);
                const unsigned a = ((e0 >> 9) & 63u) * 32u + (unsigned)(lane & 31);
                h2[a] = __hadd2(h2[a], v2);
            }
        }
    }

    // partials (fp16, layout poff*64 + b): copy as dwords
    unsigned* wp32 = reinterpret_cast<unsigned*>(
        part + ((size_t)((prgroup * WPB + w) * NDS + dslice)) * (PR_W * B_DIM));
    const unsigned* h32 = reinterpret_cast<const unsigned*>(h2);
    #pragma unroll
    for (int k = 0; k < 32; ++k)
        wp32[k * 64 + lane] = h32[k * 64 + lane];
}

// ---------------- K4: reduce partials -> out ----------------
__global__ __launch_bounds__(256) void k_reduce(
    const __half* __restrict__ part, float* __restrict__ out) {
    __shared__ float acc[16 * 65];
    const int pr = blockIdx.x;       // p-range 0..63
    const int pq = blockIdx.y;       // poff quarter 0..3
    const int t  = threadIdx.x;

    for (int i = t; i < 16 * 65; i += 256) acc[i] = 0.0f;
    __syncthreads();

    for (int ds = 0; ds < NDS; ++ds) {
        const __half* src = part + ((size_t)(pr * NDS + ds)) * (PR_W * B_DIM)
                          + pq * 16 * B_DIM;
        #pragma unroll
        for (int k = 0; k < 4; ++k) {
            const int idx = k * 256 + t;            // po_local*64 + b
            acc[(idx >> 6) * 65 + (idx & 63)] += __half2float(src[idx]);
        }
    }
    __syncthreads();

    #pragma unroll
    for (int k = 0; k < 4; ++k) {
        const int idx = k * 256 + t;
        const int po = idx & 15, b = idx >> 4;
        out[(size_t)b * P_DIM + pr * PR_W + pq * 16 + po] = acc[po * 65 + b];
    }
}

// ---------------- fallback: LDS-atomic histogram ----------------
__device__ __forceinline__ float signed_val(float x, int s) {
    return __uint_as_float(__float_as_uint(x) ^ (((unsigned)(s ^ 1)) << 31));
}

__global__ __launch_bounds__(1024) void sjlt_hist_fb(
    const float* __restrict__ x, const int* __restrict__ idx,
    const int* __restrict__ sgn, float* __restrict__ out) {
    __shared__ float hist[2][P_DIM];
    for (int i = threadIdx.x; i < 2 * P_DIM; i += 1024) (&hist[0][0])[i] = 0.0f;
    __syncthreads();
    const int chunk = blockIdx.x, bg = blockIdx.y;
    const int d0 = chunk * (D_DIM / 16), b0 = bg * 2;
    const float* xr0 = x + (size_t)b0 * D_DIM + d0;
    const float* xr1 = xr0 + D_DIM;
    const int4* iv4 = reinterpret_cast<const int4*>(idx) + d0;
    const int4* sv4 = reinterpret_cast<const int4*>(sgn) + d0;
    for (int t = threadIdx.x; t < D_DIM / 16; t += 1024) {
        const int4 iv = iv4[t]; const int4 sv = sv4[t];
        const float x0 = xr0[t], x1 = xr1[t];
        unsafeAtomicAdd(&hist[0][iv.x], signed_val(x0, sv.x));
        unsafeAtomicAdd(&hist[0][iv.y], signed_val(x0, sv.y));
        unsafeAtomicAdd(&hist[0][iv.z], signed_val(x0, sv.z));
        unsafeAtomicAdd(&hist[0][iv.w], signed_val(x0, sv.w));
        unsafeAtomicAdd(&hist[1][iv.x], signed_val(x1, sv.x));
        unsafeAtomicAdd(&hist[1][iv.y], signed_val(x1, sv.y));
        unsafeAtomicAdd(&hist[1][iv.z], signed_val(x1, sv.z));
        unsafeAtomicAdd(&hist[1][iv.w], signed_val(x1, sv.w));
    }
    __syncthreads();
    float* o = out + (size_t)b0 * P_DIM;
    for (int p = threadIdx.x; p < P_DIM; p += 1024) {
        unsafeAtomicAdd(&o[p],         hist[0][p]);
        unsafeAtomicAdd(&o[P_DIM + p], hist[1][p]);
    }
}

extern "C" void kernel_launch(void* const* d_in, const int* in_sizes, int n_in,
                              void* d_out, int out_size, void* d_ws, size_t ws_size,
                              hipStream_t stream) {
    const float* x   = (const float*)d_in[0];
    const int*   idx = (const int*)d_in[1];
    const int*   sgn = (const int*)d_in[2];
    float* out = (float*)d_out;

    if (ws_size >= WS_NEED) {
        char* ws = (char*)d_ws;
        unsigned short* pk  = (unsigned short*)(ws + PK_OFF);
        unsigned short* xTb = (unsigned short*)(ws + XT_OFF);
        __half* part = (__half*)(ws + PART_OFF);

        k_pack<<<D_DIM / 256, 256, 0, stream>>>(idx, sgn, pk);
        k_transpose<<<D_DIM / 64, 256, 0, stream>>>(x, xTb);
        k_scan<<<SCAN_BLOCKS, WPB * 64, 0, stream>>>(pk, xTb, part);
        k_reduce<<<dim3(NPR, 4), 256, 0, stream>>>(part, out);
    } else {
        hipMemsetAsync(d_out, 0, (size_t)out_size * sizeof(float), stream);
        dim3 grid(16, 32);
        sjlt_hist_fb<<<grid, 1024, 0, stream>>>(x, idx, sgn, out);
    }
}